// Round 2
// baseline (857.837 us; speedup 1.0000x reference)
//
#include <hip/hip_runtime.h>
#include <math.h>

// ---------------- model constants (double-precision derivation, f32 use) ----
static constexpr double dTS   = 1.0 / 44100.0;
static constexpr double dCM   = 12.5e-12;
static constexpr double dK    = dTS / dCM;              // Ts/CM
static constexpr double dGKF  = 19.8e-9;
static constexpr double dGKS  = 19.8e-9;
static constexpr double dEKF  = -71e-3;
static constexpr double dEKS  = -78e-3;
static constexpr double dEP   = 90e-3;
static constexpr double dGMET = 30e-9;

static constexpr float F_SCALE = (float)5.623413251903491e-06; // 10^(-105/20)
static constexpr float F_X0    = (float)20e-9;
static constexpr float F_INVS1 = (float)(1.0 / 35e-9);
static constexpr float F_INVS0 = (float)(1.0 / 16e-9);
// a = F_ANOG - F_GMK / den ;  b = F_C0 - EP * a
static constexpr float F_ANOG  = (float)(1.0 - (dGKF + dGKS) * dK);
static constexpr float F_GMK   = (float)(dGMET * dK);
static constexpr float F_EP    = (float)dEP;
static constexpr float F_C0    = (float)(dEP + (dGKF * (dEKF - dEP) + dGKS * (dEKS - dEP)) * dK);

constexpr int T_LEN = 131072;   // time samples per lane
constexpr int CHUNK = 8192;     // output samples per block
constexpr int WARM  = 1024;     // warm-up samples (a^1024 ~ 1e-33: fully converged)
constexpr int SPT   = 36;       // samples per thread: 256*36 = 8192+1024
constexpr int NTH   = 256;

typedef float v4f __attribute__((ext_vector_type(4)));  // native vec for nontemporal store

// MET conductance -> recurrence coefficient a = 1 - (G+GKF+GKS)*Ts/CM
__device__ __forceinline__ float coef(float xv) {
    float z  = fmaf(-F_SCALE, xv, F_X0);        // z = X0 - SCALE*x
    float e1 = __expf(z * F_INVS1);
    float e0 = __expf(z * F_INVS0);
    float den = fmaf(e1, e0 + 1.0f, 1.0f);      // 1 + e1*(1+e0); inf-safe -> rcp=0
    float r  = __builtin_amdgcn_rcpf(den);      // ~1 ulp, rcp(inf)=0
    return fmaf(-F_GMK, r, F_ANOG);
}

__global__ __launch_bounds__(NTH) void ihc_kernel(const float* __restrict__ x,
                                                  float* __restrict__ out,
                                                  float vpre) {
    const int c = blockIdx.x;                   // chunk index 0..15
    const int l = blockIdx.y;                   // lane index 0..399
    const int t = threadIdx.x;
    const int span_start = c * CHUNK - WARM;    // -1024 for chunk 0
    const long lbase = (long)l * T_LEN;
    const float* xp = x + lbase;
    float* op = out + lbase;
    const int tbase = span_start + t * SPT;     // global (in-lane) idx of this thread's first elem

    // ---- load 36 f32 per thread (16B-aligned float4s); clamp fake negative idx to 0
    float4 q[9];
#pragma unroll
    for (int j = 0; j < 9; ++j) {
        int a0 = tbase + 4 * j;
        int ca = a0 < 0 ? 0 : a0;
        q[j] = *reinterpret_cast<const float4*>(xp + ca);
    }

    // ---- pass 1: per-element coefficient + local affine composition (A, B)
    //      map_i(v) = a_i * v + b_i ; b_i = C0 - EP * a_i ; identity for idx < 0
    float A = 1.0f, B = 0.0f;
#pragma unroll
    for (int j = 0; j < 9; ++j) {
        float ev[4] = {q[j].x, q[j].y, q[j].z, q[j].w};
#pragma unroll
        for (int i = 0; i < 4; ++i) {
            int g = tbase + 4 * j + i;
            float a = coef(ev[i]);
            a = (g < 0) ? 1.0f : a;
            float b = (g < 0) ? 0.0f : fmaf(-F_EP, a, F_C0);
            B = fmaf(a, B, b);
            A = A * a;
            ev[i] = a;                          // keep only a; b is re-derived
        }
        q[j] = make_float4(ev[0], ev[1], ev[2], ev[3]);
    }

    // ---- block-wide exclusive affine scan (time order = thread order)
    const int lane = t & 63;
    const int w    = t >> 6;
#pragma unroll
    for (int d = 1; d < 64; d <<= 1) {          // inclusive wave scan
        float pa = __shfl_up(A, d, 64);
        float pb = __shfl_up(B, d, 64);
        if (lane >= d) { B = fmaf(A, pb, B); A = A * pa; }
    }
    __shared__ float wAs[NTH / 64], wBs[NTH / 64];
    if (lane == 63) { wAs[w] = A; wBs[w] = B; }
    __syncthreads();
    float eA = 1.0f, eB = 0.0f;                 // compose waves 0..w-1 in time order
    for (int i = 0; i < w; ++i) { eB = fmaf(wAs[i], eB, wBs[i]); eA = wAs[i] * eA; }
    float sa = __shfl_up(A, 1, 64);             // within-wave exclusive
    float sb = __shfl_up(B, 1, 64);
    if (lane == 0) { sa = 1.0f; sb = 0.0f; }

    // incoming v for this thread: WithinEx( WaveEx( vpre ) )
    float u = fmaf(eA, vpre, eB);
    float v = fmaf(sa, u, sb);

    // ---- pass 2: replay recurrence, write outputs (skip warm-up region)
#pragma unroll
    for (int j = 0; j < 9; ++j) {
        float ev[4] = {q[j].x, q[j].y, q[j].z, q[j].w};
        float ov[4];
#pragma unroll
        for (int i = 0; i < 4; ++i) {
            int g = tbase + 4 * j + i;
            float a = ev[i];
            float b = (g < 0) ? 0.0f : fmaf(-F_EP, a, F_C0);
            v = fmaf(a, v, b);
            ov[i] = v - vpre;
        }
        if (t * SPT + 4 * j >= WARM) {          // groups never straddle the boundary
            v4f o = { ov[0], ov[1], ov[2], ov[3] };
            __builtin_nontemporal_store(o, reinterpret_cast<v4f*>(op + tbase + 4 * j));
        }
    }
}

// 50 ms pre-charge relaxation, f32 forward Euler (matches reference dtype)
static float compute_vpre() {
    const float TsCM = (float)dK;
    float v = -57.03e-3f;
    for (int i = 0; i < 2205; ++i) {
        float Imet = 3.3514e-9f * (v - 0.09f);
        float Ik   = 19.8e-9f   * (v + 0.071f);
        float Is   = 19.8e-9f   * (v + 0.078f);
        v = v - (Imet + Ik + Is) * TsCM;
    }
    return v;
}

extern "C" void kernel_launch(void* const* d_in, const int* in_sizes, int n_in,
                              void* d_out, int out_size, void* d_ws, size_t ws_size,
                              hipStream_t stream) {
    const float* x = (const float*)d_in[0];
    float* out = (float*)d_out;
    const int lanes = in_sizes[0] / T_LEN;      // B*F = 400
    const int nchunks = T_LEN / CHUNK;          // 16
    float vpre = compute_vpre();                // deterministic scalar, graph-safe
    dim3 grid(nchunks, lanes);
    hipLaunchKernelGGL(ihc_kernel, grid, dim3(NTH), 0, stream, x, out, vpre);
}

// Round 3
// 355.258 us; speedup vs baseline: 2.4147x; 2.4147x over previous
//
#include <hip/hip_runtime.h>
#include <math.h>

// ---------------- model constants (double-precision derivation, f32 use) ----
static constexpr double dTS   = 1.0 / 44100.0;
static constexpr double dCM   = 12.5e-12;
static constexpr double dK    = dTS / dCM;              // Ts/CM
static constexpr double dGKF  = 19.8e-9;
static constexpr double dGKS  = 19.8e-9;
static constexpr double dEKF  = -71e-3;
static constexpr double dEKS  = -78e-3;
static constexpr double dEP   = 90e-3;
static constexpr double dGMET = 30e-9;

static constexpr float F_SCALE = (float)5.623413251903491e-06; // 10^(-105/20)
static constexpr float F_X0    = (float)20e-9;
static constexpr float F_INVS1 = (float)(1.0 / 35e-9);
static constexpr float F_INVS0 = (float)(1.0 / 16e-9);
static constexpr float F_ANOG  = (float)(1.0 - (dGKF + dGKS) * dK);
static constexpr float F_GMK   = (float)(dGMET * dK);
static constexpr float F_EP    = (float)dEP;
static constexpr float F_C0    = (float)(dEP + (dGKF * (dEKF - dEP) + dGKS * (dEKS - dEP)) * dK);

constexpr int T_LEN = 131072;   // time samples per lane
constexpr int CHUNK = 8192;     // output samples per block
constexpr int WARM  = 1024;     // warm-up samples (a^1024 ~ 1e-33: fully converged)
constexpr int SPAN  = CHUNK + WARM;  // 9216 floats staged per block (36 KB)
constexpr int SPT   = 36;       // samples per thread: 256*36 = 9216
constexpr int NTH   = 256;

typedef float v4f __attribute__((ext_vector_type(4)));

// MET conductance -> recurrence coefficient a = 1 - (G+GKF+GKS)*Ts/CM
__device__ __forceinline__ float coef(float xv) {
    float z  = fmaf(-F_SCALE, xv, F_X0);        // z = X0 - SCALE*x
    float e1 = __expf(z * F_INVS1);
    float e0 = __expf(z * F_INVS0);
    float den = fmaf(e1, e0 + 1.0f, 1.0f);      // 1 + e1*(1+e0); inf-safe -> rcp=0
    float r  = __builtin_amdgcn_rcpf(den);
    return fmaf(-F_GMK, r, F_ANOG);
}

__global__ __launch_bounds__(NTH) void ihc_kernel(const float* __restrict__ x,
                                                  float* __restrict__ out,
                                                  float vpre) {
    const int c = blockIdx.x;                   // chunk index 0..15
    const int l = blockIdx.y;                   // lane index 0..399
    const int t = threadIdx.x;
    const int span_start = c * CHUNK - WARM;    // -1024 for chunk 0
    const long lbase = (long)l * T_LEN;
    const float* xp = x + lbase;
    float* op = out + lbase;
    const int tbase = span_start + t * SPT;

    __shared__ float lbuf[SPAN];                // 36 KB staging (input, then output)
    float4* lb4 = reinterpret_cast<float4*>(lbuf);

    // ---- Phase A: coalesced global -> LDS (lane i reads consecutive float4)
#pragma unroll
    for (int j = 0; j < 9; ++j) {
        int g  = t + NTH * j;                   // float4 group 0..2303
        int a0 = span_start + 4 * g;
        int ca = a0 < 0 ? 0 : a0;               // clamp fake negative idx (masked later)
        lb4[g] = *reinterpret_cast<const float4*>(xp + ca);
    }
    __syncthreads();

    // ---- Phase B: LDS -> registers (own contiguous 36-float run)
    float4 q[9];
#pragma unroll
    for (int j = 0; j < 9; ++j) q[j] = lb4[t * 9 + j];

    // ---- pass 1: per-element coefficient + local affine composition (A, B)
    float A = 1.0f, B = 0.0f;
#pragma unroll
    for (int j = 0; j < 9; ++j) {
        float ev[4] = {q[j].x, q[j].y, q[j].z, q[j].w};
#pragma unroll
        for (int i = 0; i < 4; ++i) {
            int g = tbase + 4 * j + i;
            float a = coef(ev[i]);
            a = (g < 0) ? 1.0f : a;
            float b = (g < 0) ? 0.0f : fmaf(-F_EP, a, F_C0);
            B = fmaf(a, B, b);
            A = A * a;
            ev[i] = a;
        }
        q[j] = make_float4(ev[0], ev[1], ev[2], ev[3]);
    }

    // ---- block-wide exclusive affine scan (time order = thread order)
    const int lane = t & 63;
    const int w    = t >> 6;
#pragma unroll
    for (int d = 1; d < 64; d <<= 1) {
        float pa = __shfl_up(A, d, 64);
        float pb = __shfl_up(B, d, 64);
        if (lane >= d) { B = fmaf(A, pb, B); A = A * pa; }
    }
    __shared__ float wAs[NTH / 64], wBs[NTH / 64];
    if (lane == 63) { wAs[w] = A; wBs[w] = B; }
    __syncthreads();                            // also orders B-reads before D-writes
    float eA = 1.0f, eB = 0.0f;
    for (int i = 0; i < w; ++i) { eB = fmaf(wAs[i], eB, wBs[i]); eA = wAs[i] * eA; }
    float sa = __shfl_up(A, 1, 64);
    float sb = __shfl_up(B, 1, 64);
    if (lane == 0) { sa = 1.0f; sb = 0.0f; }

    float u = fmaf(eA, vpre, eB);
    float v = fmaf(sa, u, sb);

    // ---- Phase D: replay recurrence, write outputs into LDS (skip warm-up)
#pragma unroll
    for (int j = 0; j < 9; ++j) {
        float ev[4] = {q[j].x, q[j].y, q[j].z, q[j].w};
        float ov[4];
#pragma unroll
        for (int i = 0; i < 4; ++i) {
            int g = tbase + 4 * j + i;
            float a = ev[i];
            float b = (g < 0) ? 0.0f : fmaf(-F_EP, a, F_C0);
            v = fmaf(a, v, b);
            ov[i] = v - vpre;
        }
        int pos = t * SPT + 4 * j - WARM;       // output float idx within chunk
        if (pos >= 0)                           // groups never straddle the boundary
            lb4[pos >> 2] = make_float4(ov[0], ov[1], ov[2], ov[3]);
    }
    __syncthreads();

    // ---- Phase E: coalesced LDS -> global (full-line nontemporal stores)
    float* opc = op + c * CHUNK;
#pragma unroll
    for (int j = 0; j < 8; ++j) {
        int g = t + NTH * j;                    // float4 group 0..2047
        float4 o = lb4[g];
        v4f ov = { o.x, o.y, o.z, o.w };
        __builtin_nontemporal_store(ov, reinterpret_cast<v4f*>(opc + 4 * g));
    }
}

// 50 ms pre-charge relaxation, f32 forward Euler (matches reference dtype)
static float compute_vpre() {
    const float TsCM = (float)dK;
    float v = -57.03e-3f;
    for (int i = 0; i < 2205; ++i) {
        float Imet = 3.3514e-9f * (v - 0.09f);
        float Ik   = 19.8e-9f   * (v + 0.071f);
        float Is   = 19.8e-9f   * (v + 0.078f);
        v = v - (Imet + Ik + Is) * TsCM;
    }
    return v;
}

extern "C" void kernel_launch(void* const* d_in, const int* in_sizes, int n_in,
                              void* d_out, int out_size, void* d_ws, size_t ws_size,
                              hipStream_t stream) {
    const float* x = (const float*)d_in[0];
    float* out = (float*)d_out;
    const int lanes = in_sizes[0] / T_LEN;      // B*F = 400
    const int nchunks = T_LEN / CHUNK;          // 16
    float vpre = compute_vpre();                // deterministic scalar, graph-safe
    dim3 grid(nchunks, lanes);
    hipLaunchKernelGGL(ihc_kernel, grid, dim3(NTH), 0, stream, x, out, vpre);
}